// Round 2
// baseline (2202.493 us; speedup 1.0000x reference)
//
#include <hip/hip_runtime.h>
#include <hip/hip_bf16.h>
#include <cstddef>
#include <cstdint>

#define HIDDEN 1024
#define H2     2048
#define NEXP   8
#define NTOK   8192

// ---------------- helpers: typed 4-wide load/store (float or bf16) ----------
__device__ __forceinline__ float4 ld4(const float* p) {
    return *reinterpret_cast<const float4*>(p);
}
__device__ __forceinline__ float4 ld4(const __hip_bfloat16* p) {
    ushort4 u = *reinterpret_cast<const ushort4*>(p);
    __hip_bfloat16 t0, t1, t2, t3;
    __builtin_memcpy(&t0, &u.x, 2); __builtin_memcpy(&t1, &u.y, 2);
    __builtin_memcpy(&t2, &u.z, 2); __builtin_memcpy(&t3, &u.w, 2);
    float4 f;
    f.x = __bfloat162float(t0); f.y = __bfloat162float(t1);
    f.z = __bfloat162float(t2); f.w = __bfloat162float(t3);
    return f;
}
__device__ __forceinline__ void st4(float* p, float4 v) {
    *reinterpret_cast<float4*>(p) = v;
}
__device__ __forceinline__ void st4(__hip_bfloat16* p, float4 v) {
    __hip_bfloat16 t0 = __float2bfloat16(v.x), t1 = __float2bfloat16(v.y);
    __hip_bfloat16 t2 = __float2bfloat16(v.z), t3 = __float2bfloat16(v.w);
    ushort4 u;
    __builtin_memcpy(&u.x, &t0, 2); __builtin_memcpy(&u.y, &t1, 2);
    __builtin_memcpy(&u.z, &t2, 2); __builtin_memcpy(&u.w, &t3, 2);
    *reinterpret_cast<ushort4*>(p) = u;
}

// ---------------- zero output + histogram counters ---------------------------
__global__ void zero_kernel(float4* __restrict__ out4, long n4, int* __restrict__ cnt) {
    long i = (long)blockIdx.x * blockDim.x + threadIdx.x;
    long stride = (long)gridDim.x * blockDim.x;
    float4 z; z.x = z.y = z.z = z.w = 0.f;
    for (; i < n4; i += stride) out4[i] = z;
    if (blockIdx.x == 0 && threadIdx.x < NEXP) cnt[threadIdx.x] = 0;
}

// ---------------- router: 1 wave per token ----------------------------------
__global__ __launch_bounds__(64) void router_kernel(
    const float* __restrict__ x, const float* __restrict__ Wr,
    const float* __restrict__ br, int* __restrict__ cnt,
    int* __restrict__ tok_e, float* __restrict__ tok_g)
{
    const int t = blockIdx.x;
    const int lane = threadIdx.x;
    const float* __restrict__ xr = x + (size_t)t * HIDDEN;
    float acc[NEXP];
#pragma unroll
    for (int e = 0; e < NEXP; ++e) acc[e] = 0.f;
#pragma unroll
    for (int i = 0; i < HIDDEN / 64; ++i) {
        int d = i * 64 + lane;                // coalesced across lanes
        float xv = xr[d];
        const float* wrow = Wr + (size_t)d * NEXP;
        float4 w0 = ld4(wrow);
        float4 w1 = ld4(wrow + 4);
        acc[0] = fmaf(xv, w0.x, acc[0]); acc[1] = fmaf(xv, w0.y, acc[1]);
        acc[2] = fmaf(xv, w0.z, acc[2]); acc[3] = fmaf(xv, w0.w, acc[3]);
        acc[4] = fmaf(xv, w1.x, acc[4]); acc[5] = fmaf(xv, w1.y, acc[5]);
        acc[6] = fmaf(xv, w1.z, acc[6]); acc[7] = fmaf(xv, w1.w, acc[7]);
    }
#pragma unroll
    for (int off = 32; off > 0; off >>= 1)
#pragma unroll
        for (int e = 0; e < NEXP; ++e) acc[e] += __shfl_xor(acc[e], off);

    if (lane == 0) {
        float l[NEXP];
#pragma unroll
        for (int e = 0; e < NEXP; ++e) l[e] = acc[e] + br[e];
        // top-2; ties -> lower index (matches jax.lax.top_k)
        int e0 = 0;
#pragma unroll
        for (int e = 1; e < NEXP; ++e) if (l[e] > l[e0]) e0 = e;
        int e1 = (e0 == 0) ? 1 : 0;
#pragma unroll
        for (int e = 0; e < NEXP; ++e) if (e != e0 && l[e] > l[e1]) e1 = e;
        // renormalized top-2 gates: softmax denominators cancel;
        // l[e0] >= l[e1] so exp arg <= 0 (stable).
        float g0 = 1.0f / (1.0f + expf(l[e1] - l[e0]));
        tok_e[t] = e0 | (e1 << 8);
        tok_g[t] = g0;
        atomicAdd(&cnt[e0], 1);
        atomicAdd(&cnt[e1], 1);
    }
}

// ---------------- 8-entry prefix scan + zero placement counters --------------
__global__ void scan_kernel(const int* __restrict__ cnt, int* __restrict__ offs,
                            int* __restrict__ cnt2) {
    if (threadIdx.x == 0) {
        int s = 0;
#pragma unroll
        for (int e = 0; e < NEXP; ++e) { offs[e] = s; s += cnt[e]; }
        offs[NEXP] = s;
    }
    if (threadIdx.x < NEXP) cnt2[threadIdx.x] = 0;
}

// ---------------- build per-expert gathered token/gate lists -----------------
__global__ void build_lists(const int* __restrict__ tok_e, const float* __restrict__ tok_g,
                            const int* __restrict__ offs, int* __restrict__ cnt2,
                            int* __restrict__ tok_list, float* __restrict__ gate_list)
{
    int t = blockIdx.x * blockDim.x + threadIdx.x;
    if (t >= NTOK) return;
    int pk = tok_e[t];
    float g0 = tok_g[t];
    int e0 = pk & 0xff, e1 = (pk >> 8) & 0xff;
    int p0 = atomicAdd(&cnt2[e0], 1);
    int r0 = offs[e0] + p0;
    tok_list[r0] = t; gate_list[r0] = g0;
    int p1 = atomicAdd(&cnt2[e1], 1);
    int r1 = offs[e1] + p1;
    tok_list[r1] = t; gate_list[r1] = 1.0f - g0;
}

// ---------------- GEMM1: h = relu(gather(x) @ W1[e] + b1[e]) -----------------
// 64x64 tile, BK=16, 256 threads, 4x4 micro-tile.
template <typename HT>
__global__ __launch_bounds__(256) void gemm1_kernel(
    const float* __restrict__ x, const float* __restrict__ W1,
    const float* __restrict__ b1, const int* __restrict__ offs,
    const int* __restrict__ tok_list, HT* __restrict__ h)
{
    const int e = blockIdx.z;
    const int rbase = offs[e];
    const int rows = offs[e + 1] - rbase;
    const int rt = blockIdx.y * 64;
    if (rt >= rows) return;
    const int ct = blockIdx.x * 64;
    const float* __restrict__ W = W1 + (size_t)e * HIDDEN * H2;

    __shared__ __align__(16) float As[16][68];   // [k][m]
    __shared__ __align__(16) float Bs[16][68];   // [k][n]

    const int tid = threadIdx.x;
    const int rowA = tid >> 2;          // 0..63
    const int kA = (tid & 3) << 2;      // 0,4,8,12
    int r = rt + rowA;
    int rc = (r < rows) ? r : 0;        // clamp: computed but never stored
    const float* __restrict__ aptr = x + (size_t)tok_list[rbase + rc] * HIDDEN + kA;

    const int kB = tid >> 4;            // 0..15
    const int nB = (tid & 15) << 2;     // 0..60
    const float* __restrict__ bptr = W + (size_t)kB * H2 + ct + nB;

    const int tm = (tid & 15) << 2;     // row of micro-tile
    const int tn = (tid >> 4) << 2;     // col of micro-tile

    float acc[4][4] = {};

    for (int k0 = 0; k0 < HIDDEN; k0 += 16) {
        float4 a = ld4(aptr + k0);
        float4 b = ld4(bptr + (size_t)k0 * H2);
        __syncthreads();
        As[kA + 0][rowA] = a.x; As[kA + 1][rowA] = a.y;
        As[kA + 2][rowA] = a.z; As[kA + 3][rowA] = a.w;
        *reinterpret_cast<float4*>(&Bs[kB][nB]) = b;
        __syncthreads();
#pragma unroll
        for (int k = 0; k < 16; ++k) {
            float a4[4], b4[4];
            *reinterpret_cast<float4*>(a4) = *reinterpret_cast<const float4*>(&As[k][tm]);
            *reinterpret_cast<float4*>(b4) = *reinterpret_cast<const float4*>(&Bs[k][tn]);
#pragma unroll
            for (int i = 0; i < 4; ++i)
#pragma unroll
                for (int j = 0; j < 4; ++j)
                    acc[i][j] = fmaf(a4[i], b4[j], acc[i][j]);
        }
    }

    float4 bias = ld4(b1 + (size_t)e * H2 + ct + tn);
#pragma unroll
    for (int i = 0; i < 4; ++i) {
        int rr = rt + tm + i;
        if (rr >= rows) continue;
        float4 v;
        v.x = fmaxf(acc[i][0] + bias.x, 0.f);
        v.y = fmaxf(acc[i][1] + bias.y, 0.f);
        v.z = fmaxf(acc[i][2] + bias.z, 0.f);
        v.w = fmaxf(acc[i][3] + bias.w, 0.f);
        st4(h + (size_t)(rbase + rr) * H2 + ct + tn, v);
    }
}

// ---------------- GEMM2: out[tok] += gate * (h @ W2[e] + b2[e]) --------------
template <typename HT>
__global__ __launch_bounds__(256) void gemm2_kernel(
    const HT* __restrict__ h, const float* __restrict__ W2,
    const float* __restrict__ b2, const int* __restrict__ offs,
    const int* __restrict__ tok_list, const float* __restrict__ gate_list,
    float* __restrict__ out)
{
    const int e = blockIdx.z;
    const int rbase = offs[e];
    const int rows = offs[e + 1] - rbase;
    const int rt = blockIdx.y * 64;
    if (rt >= rows) return;
    const int ct = blockIdx.x * 64;
    const float* __restrict__ W = W2 + (size_t)e * H2 * HIDDEN;

    __shared__ __align__(16) float As[16][68];
    __shared__ __align__(16) float Bs[16][68];

    const int tid = threadIdx.x;
    const int rowA = tid >> 2;
    const int kA = (tid & 3) << 2;
    int r = rt + rowA;
    int rc = (r < rows) ? r : 0;
    const HT* __restrict__ aptr = h + (size_t)(rbase + rc) * H2 + kA;

    const int kB = tid >> 4;
    const int nB = (tid & 15) << 2;
    const float* __restrict__ bptr = W + (size_t)kB * HIDDEN + ct + nB;

    const int tm = (tid & 15) << 2;
    const int tn = (tid >> 4) << 2;

    float acc[4][4] = {};

    for (int k0 = 0; k0 < H2; k0 += 16) {
        float4 a = ld4(aptr + k0);
        float4 b = ld4(bptr + (size_t)k0 * HIDDEN);
        __syncthreads();
        As[kA + 0][rowA] = a.x; As[kA + 1][rowA] = a.y;
        As[kA + 2][rowA] = a.z; As[kA + 3][rowA] = a.w;
        *reinterpret_cast<float4*>(&Bs[kB][nB]) = b;
        __syncthreads();
#pragma unroll
        for (int k = 0; k < 16; ++k) {
            float a4[4], b4[4];
            *reinterpret_cast<float4*>(a4) = *reinterpret_cast<const float4*>(&As[k][tm]);
            *reinterpret_cast<float4*>(b4) = *reinterpret_cast<const float4*>(&Bs[k][tn]);
#pragma unroll
            for (int i = 0; i < 4; ++i)
#pragma unroll
                for (int j = 0; j < 4; ++j)
                    acc[i][j] = fmaf(a4[i], b4[j], acc[i][j]);
        }
    }

    float4 bias = ld4(b2 + (size_t)e * HIDDEN + ct + tn);
#pragma unroll
    for (int i = 0; i < 4; ++i) {
        int rr = rt + tm + i;
        if (rr >= rows) continue;
        int row = rbase + rr;
        int tok = tok_list[row];
        float g = gate_list[row];
        float* op = out + (size_t)tok * HIDDEN + ct + tn;
        atomicAdd(op + 0, g * (acc[i][0] + bias.x));
        atomicAdd(op + 1, g * (acc[i][1] + bias.y));
        atomicAdd(op + 2, g * (acc[i][2] + bias.z));
        atomicAdd(op + 3, g * (acc[i][3] + bias.w));
    }
}

// ---------------- host launcher ----------------------------------------------
extern "C" void kernel_launch(void* const* d_in, const int* in_sizes, int n_in,
                              void* d_out, int out_size, void* d_ws, size_t ws_size,
                              hipStream_t stream)
{
    const float* x  = (const float*)d_in[0];
    const float* Wr = (const float*)d_in[1];
    const float* br = (const float*)d_in[2];
    const float* W1 = (const float*)d_in[3];
    const float* b1 = (const float*)d_in[4];
    const float* W2 = (const float*)d_in[5];
    const float* b2 = (const float*)d_in[6];
    float* out = (float*)d_out;

    char* ws = (char*)d_ws;
    int*   cnt       = (int*)ws;                 // 8
    int*   cnt2      = cnt + 8;                  // 8
    int*   offs      = cnt + 16;                 // 9
    int*   tok_e     = (int*)(ws + 128);                         // NTOK
    float* tok_g     = (float*)(ws + 128 + (size_t)NTOK * 4);    // NTOK
    int*   tok_list  = (int*)(ws + 128 + (size_t)NTOK * 8);      // 2*NTOK
    float* gate_list = (float*)(ws + 128 + (size_t)NTOK * 8 + (size_t)2 * NTOK * 4);
    size_t hoff = ((size_t)128 + (size_t)NTOK * 8 + (size_t)2 * NTOK * 8 + 255) & ~(size_t)255;
    size_t need_f32 = hoff + (size_t)2 * NTOK * H2 * 4;
    bool h_is_f32 = (ws_size >= need_f32);

    zero_kernel<<<2048, 256, 0, stream>>>((float4*)out, (long)NTOK * HIDDEN / 4, cnt);
    router_kernel<<<NTOK, 64, 0, stream>>>(x, Wr, br, cnt, tok_e, tok_g);
    scan_kernel<<<1, 64, 0, stream>>>(cnt, offs, cnt2);
    build_lists<<<(NTOK + 255) / 256, 256, 0, stream>>>(tok_e, tok_g, offs, cnt2,
                                                        tok_list, gate_list);

    dim3 g1(H2 / 64, NTOK / 64, NEXP);      // col-tiles, row-tiles(worst case), experts
    dim3 g2(HIDDEN / 64, NTOK / 64, NEXP);
    if (h_is_f32) {
        float* h = (float*)(ws + hoff);
        gemm1_kernel<float><<<g1, 256, 0, stream>>>(x, W1, b1, offs, tok_list, h);
        gemm2_kernel<float><<<g2, 256, 0, stream>>>(h, W2, b2, offs, tok_list, gate_list, out);
    } else {
        __hip_bfloat16* h = (__hip_bfloat16*)(ws + hoff);
        gemm1_kernel<__hip_bfloat16><<<g1, 256, 0, stream>>>(x, W1, b1, offs, tok_list, h);
        gemm2_kernel<__hip_bfloat16><<<g2, 256, 0, stream>>>(h, W2, b2, offs, tok_list, gate_list, out);
    }
}

// Round 4
// 934.060 us; speedup vs baseline: 2.3580x; 2.3580x over previous
//
#include <hip/hip_runtime.h>
#include <hip/hip_bf16.h>
#include <cstddef>
#include <cstdint>

#define HIDDEN 1024
#define H2     2048
#define NEXP   8
#define NTOK   8192

typedef __attribute__((ext_vector_type(8))) short bf16x8;
typedef __attribute__((ext_vector_type(4))) float f32x4;

// ---------------- helpers ----------------------------------------------------
__device__ __forceinline__ float4 ld4f(const float* p) {
    return *reinterpret_cast<const float4*>(p);
}
__device__ __forceinline__ unsigned short f2bf(float f) {
    __hip_bfloat16 b = __float2bfloat16(f);
    unsigned short u; __builtin_memcpy(&u, &b, 2); return u;
}
__device__ __forceinline__ unsigned pk2(float a, float b) {
    return (unsigned)f2bf(a) | ((unsigned)f2bf(b) << 16);
}

// ---------------- zero output + histogram counters ---------------------------
__global__ void zero_kernel(float4* __restrict__ out4, long n4, int* __restrict__ cnt) {
    long i = (long)blockIdx.x * blockDim.x + threadIdx.x;
    long stride = (long)gridDim.x * blockDim.x;
    float4 z; z.x = z.y = z.z = z.w = 0.f;
    for (; i < n4; i += stride) out4[i] = z;
    if (blockIdx.x == 0 && threadIdx.x < NEXP) cnt[threadIdx.x] = 0;
}

// ---------------- router: 1 wave per token ----------------------------------
__global__ __launch_bounds__(64) void router_kernel(
    const float* __restrict__ x, const float* __restrict__ Wr,
    const float* __restrict__ br, int* __restrict__ cnt,
    int* __restrict__ tok_e, float* __restrict__ tok_g)
{
    const int t = blockIdx.x;
    const int lane = threadIdx.x;
    const float* __restrict__ xr = x + (size_t)t * HIDDEN;
    float acc[NEXP];
#pragma unroll
    for (int e = 0; e < NEXP; ++e) acc[e] = 0.f;
#pragma unroll
    for (int i = 0; i < HIDDEN / 64; ++i) {
        int d = i * 64 + lane;
        float xv = xr[d];
        const float* wrow = Wr + (size_t)d * NEXP;
        float4 w0 = ld4f(wrow);
        float4 w1 = ld4f(wrow + 4);
        acc[0] = fmaf(xv, w0.x, acc[0]); acc[1] = fmaf(xv, w0.y, acc[1]);
        acc[2] = fmaf(xv, w0.z, acc[2]); acc[3] = fmaf(xv, w0.w, acc[3]);
        acc[4] = fmaf(xv, w1.x, acc[4]); acc[5] = fmaf(xv, w1.y, acc[5]);
        acc[6] = fmaf(xv, w1.z, acc[6]); acc[7] = fmaf(xv, w1.w, acc[7]);
    }
#pragma unroll
    for (int off = 32; off > 0; off >>= 1)
#pragma unroll
        for (int e = 0; e < NEXP; ++e) acc[e] += __shfl_xor(acc[e], off);

    if (lane == 0) {
        float l[NEXP];
#pragma unroll
        for (int e = 0; e < NEXP; ++e) l[e] = acc[e] + br[e];
        int e0 = 0;
#pragma unroll
        for (int e = 1; e < NEXP; ++e) if (l[e] > l[e0]) e0 = e;
        int e1 = (e0 == 0) ? 1 : 0;
#pragma unroll
        for (int e = 0; e < NEXP; ++e) if (e != e0 && l[e] > l[e1]) e1 = e;
        float g0 = 1.0f / (1.0f + expf(l[e1] - l[e0]));
        tok_e[t] = e0 | (e1 << 8);
        tok_g[t] = g0;
        atomicAdd(&cnt[e0], 1);
        atomicAdd(&cnt[e1], 1);
    }
}

// ---------------- 8-entry prefix scan + zero placement counters --------------
__global__ void scan_kernel(const int* __restrict__ cnt, int* __restrict__ offs,
                            int* __restrict__ cnt2) {
    if (threadIdx.x == 0) {
        int s = 0;
#pragma unroll
        for (int e = 0; e < NEXP; ++e) { offs[e] = s; s += cnt[e]; }
        offs[NEXP] = s;
    }
    if (threadIdx.x < NEXP) cnt2[threadIdx.x] = 0;
}

// ---------------- build per-expert gathered token/gate lists -----------------
__global__ void build_lists(const int* __restrict__ tok_e, const float* __restrict__ tok_g,
                            const int* __restrict__ offs, int* __restrict__ cnt2,
                            int* __restrict__ tok_list, float* __restrict__ gate_list)
{
    int t = blockIdx.x * blockDim.x + threadIdx.x;
    if (t >= NTOK) return;
    int pk = tok_e[t];
    float g0 = tok_g[t];
    int e0 = pk & 0xff, e1 = (pk >> 8) & 0xff;
    int p0 = atomicAdd(&cnt2[e0], 1);
    int r0 = offs[e0] + p0;
    tok_list[r0] = t; gate_list[r0] = g0;
    int p1 = atomicAdd(&cnt2[e1], 1);
    int r1 = offs[e1] + p1;
    tok_list[r1] = t; gate_list[r1] = 1.0f - g0;
}

// ---------------- MFMA GEMM: C = A @ W[e] (+bias, relu|gate-scatter) ---------
// 128x128 tile, BK=32, 256 threads = 4 waves (2x2), wave = 4x4 frags of
// 16x16x32 bf16 MFMA. A: [rows][K] (f32 gathered x, or bf16 h). W: [E][K][N]
// f32, reg-staged TRANSPOSED into Bs[n][k] bf16. LDS [128][32] bf16 per
// operand with slot-XOR swizzle (slot ^= row&3) to spread banks.
template <int K, int N, bool GATHER, bool EPI2, typename AT>
__global__ __launch_bounds__(256) void moe_gemm_mfma(
    const AT* __restrict__ Abase,
    const float* __restrict__ Wall,
    const float* __restrict__ biasall,
    const int* __restrict__ offs,
    const int* __restrict__ tok_list,
    const float* __restrict__ gate_list,
    void* __restrict__ outp)
{
    const int e = blockIdx.z;
    const int rbase = offs[e];
    const int rows = offs[e + 1] - rbase;
    const int rt = blockIdx.y * 128;
    if (rt >= rows) return;
    const int ct = blockIdx.x * 128;
    const float* __restrict__ W = Wall + (size_t)e * K * N;

    __shared__ unsigned short As[128][32];
    __shared__ unsigned short Bs[128][32];

    const int tid = threadIdx.x;
    const int lane = tid & 63;
    const int wv = tid >> 6;
    const int wr = wv >> 1, wc = wv & 1;

    // staging roles: thread -> (row 0..127, k-half 0..1)
    const int srow = tid >> 1;
    const int skh = tid & 1;
    int ar = rt + srow; if (ar > rows - 1) ar = rows - 1;
    const AT* __restrict__ aptr;
    if (GATHER) aptr = Abase + (size_t)tok_list[rbase + ar] * K + skh * 16;
    else        aptr = Abase + (size_t)(rbase + ar) * K + skh * 16;
    const float* __restrict__ bptr = W + (size_t)skh * 16 * N + ct + srow;

    // swizzled LDS short-index targets for this thread's two 16B writes
    const int sA0 = (((skh << 1) | 0) ^ (srow & 3)) * 8;
    const int sA1 = (((skh << 1) | 1) ^ (srow & 3)) * 8;

    f32x4 acc[4][4];
    const f32x4 vz = {0.f, 0.f, 0.f, 0.f};
#pragma unroll
    for (int m = 0; m < 4; ++m)
#pragma unroll
        for (int n = 0; n < 4; ++n) acc[m][n] = vz;

    const int fr = lane & 15;   // fragment row/col within 16
    const int fs = lane >> 4;   // k-slot 0..3

    for (int k0 = 0; k0 < K; k0 += 32) {
        // ---- global loads (issued before barrier: overlap w/ prev MFMA) ----
        uint4 wa0, wa1;
        if constexpr (sizeof(AT) == 4) {          // f32 A -> convert
            const float* ap = (const float*)aptr + k0;
            float4 a0 = ld4f(ap), a1 = ld4f(ap + 4), a2 = ld4f(ap + 8), a3 = ld4f(ap + 12);
            wa0 = make_uint4(pk2(a0.x, a0.y), pk2(a0.z, a0.w), pk2(a1.x, a1.y), pk2(a1.z, a1.w));
            wa1 = make_uint4(pk2(a2.x, a2.y), pk2(a2.z, a2.w), pk2(a3.x, a3.y), pk2(a3.z, a3.w));
        } else {                                   // bf16 A -> raw copy
            wa0 = *reinterpret_cast<const uint4*>(aptr + k0);
            wa1 = *reinterpret_cast<const uint4*>(aptr + k0 + 8);
        }
        float bfv[16];
#pragma unroll
        for (int j = 0; j < 16; ++j) bfv[j] = bptr[(size_t)(k0 + j) * N];
        uint4 wb0 = make_uint4(pk2(bfv[0], bfv[1]), pk2(bfv[2], bfv[3]),
                               pk2(bfv[4], bfv[5]), pk2(bfv[6], bfv[7]));
        uint4 wb1 = make_uint4(pk2(bfv[8], bfv[9]), pk2(bfv[10], bfv[11]),
                               pk2(bfv[12], bfv[13]), pk2(bfv[14], bfv[15]));

        __syncthreads();   // all waves done reading LDS from previous step
        *reinterpret_cast<uint4*>(&As[srow][sA0]) = wa0;
        *reinterpret_cast<uint4*>(&As[srow][sA1]) = wa1;
        *reinterpret_cast<uint4*>(&Bs[srow][sA0]) = wb0;
        *reinterpret_cast<uint4*>(&Bs[srow][sA1]) = wb1;
        __syncthreads();   // tile visible

        bf16x8 af[4], bfr[4];
#pragma unroll
        for (int m = 0; m < 4; ++m) {
            int r = wr * 64 + m * 16 + fr;
            af[m] = *reinterpret_cast<const bf16x8*>(&As[r][(fs ^ (r & 3)) * 8]);
        }
#pragma unroll
        for (int n = 0; n < 4; ++n) {
            int c = wc * 64 + n * 16 + fr;
            bfr[n] = *reinterpret_cast<const bf16x8*>(&Bs[c][(fs ^ (c & 3)) * 8]);
        }
#pragma unroll
        for (int m = 0; m < 4; ++m)
#pragma unroll
            for (int n = 0; n < 4; ++n)
                acc[m][n] = __builtin_amdgcn_mfma_f32_16x16x32_bf16(af[m], bfr[n], acc[m][n], 0, 0, 0);
    }

    // ---- epilogue: C/D map col=lane&15, row=(lane>>4)*4+j (m89 verified) ----
    float bv[4];
#pragma unroll
    for (int n = 0; n < 4; ++n)
        bv[n] = biasall[(size_t)e * N + ct + wc * 64 + n * 16 + fr];

    if constexpr (!EPI2) {
        __hip_bfloat16* h = (__hip_bfloat16*)outp;
#pragma unroll
        for (int m = 0; m < 4; ++m)
#pragma unroll
            for (int j = 0; j < 4; ++j) {
                int rl = rt + wr * 64 + m * 16 + fs * 4 + j;
                if (rl >= rows) continue;
                size_t ro = (size_t)(rbase + rl) * N + ct + wc * 64 + fr;
#pragma unroll
                for (int n = 0; n < 4; ++n) {
                    float v = acc[m][n][j] + bv[n];
                    h[ro + n * 16] = __float2bfloat16(fmaxf(v, 0.f));
                }
            }
    } else {
        float* out = (float*)outp;
#pragma unroll
        for (int m = 0; m < 4; ++m)
#pragma unroll
            for (int j = 0; j < 4; ++j) {
                int rl = rt + wr * 64 + m * 16 + fs * 4 + j;
                if (rl >= rows) continue;
                int rr = rbase + rl;
                int tok = tok_list[rr];
                float g = gate_list[rr];
                size_t o = (size_t)tok * N + ct + wc * 64 + fr;
#pragma unroll
                for (int n = 0; n < 4; ++n)
                    atomicAdd(&out[o + n * 16], g * (acc[m][n][j] + bv[n]));
            }
    }
}

// ---------------- host launcher ----------------------------------------------
extern "C" void kernel_launch(void* const* d_in, const int* in_sizes, int n_in,
                              void* d_out, int out_size, void* d_ws, size_t ws_size,
                              hipStream_t stream)
{
    const float* x  = (const float*)d_in[0];
    const float* Wr = (const float*)d_in[1];
    const float* br = (const float*)d_in[2];
    const float* W1 = (const float*)d_in[3];
    const float* b1 = (const float*)d_in[4];
    const float* W2 = (const float*)d_in[5];
    const float* b2 = (const float*)d_in[6];
    float* out = (float*)d_out;

    char* ws = (char*)d_ws;
    int*   cnt       = (int*)ws;                 // 8
    int*   cnt2      = cnt + 8;                  // 8
    int*   offs      = cnt + 16;                 // 9
    int*   tok_e     = (int*)(ws + 128);                         // NTOK
    float* tok_g     = (float*)(ws + 128 + (size_t)NTOK * 4);    // NTOK
    int*   tok_list  = (int*)(ws + 128 + (size_t)NTOK * 8);      // 2*NTOK
    float* gate_list = (float*)(ws + 128 + (size_t)NTOK * 8 + (size_t)2 * NTOK * 4);
    size_t hoff = ((size_t)128 + (size_t)NTOK * 8 + (size_t)2 * NTOK * 8 + 255) & ~(size_t)255;
    __hip_bfloat16* h = (__hip_bfloat16*)(ws + hoff);   // [2*NTOK][H2] bf16, ~67 MB

    zero_kernel<<<2048, 256, 0, stream>>>((float4*)out, (long)NTOK * HIDDEN / 4, cnt);
    router_kernel<<<NTOK, 64, 0, stream>>>(x, Wr, br, cnt, tok_e, tok_g);
    scan_kernel<<<1, 64, 0, stream>>>(cnt, offs, cnt2);
    build_lists<<<(NTOK + 255) / 256, 256, 0, stream>>>(tok_e, tok_g, offs, cnt2,
                                                        tok_list, gate_list);

    dim3 g1(H2 / 128, NTOK / 128, NEXP);      // 16 x 64 x 8 (tail tiles early-exit)
    dim3 g2(HIDDEN / 128, NTOK / 128, NEXP);  //  8 x 64 x 8
    moe_gemm_mfma<HIDDEN, H2, true,  false, float>
        <<<g1, 256, 0, stream>>>(x, W1, b1, offs, tok_list, gate_list, (void*)h);
    moe_gemm_mfma<H2, HIDDEN, false, true, __hip_bfloat16>
        <<<g2, 256, 0, stream>>>(h, W2, b2, offs, tok_list, gate_list, (void*)out);
}

// Round 6
// 682.599 us; speedup vs baseline: 3.2266x; 1.3684x over previous
//
#include <hip/hip_runtime.h>
#include <hip/hip_bf16.h>
#include <cstddef>
#include <cstdint>

#define HIDDEN 1024
#define H2     2048
#define NEXP   8
#define NTOK   8192

typedef __attribute__((ext_vector_type(8))) short bf16x8;
typedef __attribute__((ext_vector_type(4))) float f32x4;

// ---------------- helpers ----------------------------------------------------
__device__ __forceinline__ float4 ld4f(const float* p) {
    return *reinterpret_cast<const float4*>(p);
}
__device__ __forceinline__ unsigned short f2bf(float f) {
    __hip_bfloat16 b = __float2bfloat16(f);
    unsigned short u; __builtin_memcpy(&u, &b, 2); return u;
}
__device__ __forceinline__ unsigned pk2(float a, float b) {
    return (unsigned)f2bf(a) | ((unsigned)f2bf(b) << 16);
}

// ---------------- zero output + counters -------------------------------------
__global__ void zero_kernel(float4* __restrict__ out4, long n4, int* __restrict__ cnt) {
    long i = (long)blockIdx.x * blockDim.x + threadIdx.x;
    long stride = (long)gridDim.x * blockDim.x;
    float4 z; z.x = z.y = z.z = z.w = 0.f;
    for (; i < n4; i += stride) out4[i] = z;
    if (blockIdx.x == 0 && threadIdx.x < 2 * NEXP) cnt[threadIdx.x] = 0;
}

// ---------------- router: 1 wave per token (no atomics) ----------------------
__global__ __launch_bounds__(64) void router_kernel(
    const float* __restrict__ x, const float* __restrict__ Wr,
    const float* __restrict__ br,
    int* __restrict__ tok_e, float* __restrict__ tok_g)
{
    const int t = blockIdx.x;
    const int lane = threadIdx.x;
    const float* __restrict__ xr = x + (size_t)t * HIDDEN;
    float acc[NEXP];
#pragma unroll
    for (int e = 0; e < NEXP; ++e) acc[e] = 0.f;
#pragma unroll
    for (int i = 0; i < HIDDEN / 64; ++i) {
        int d = i * 64 + lane;
        float xv = xr[d];
        const float* wrow = Wr + (size_t)d * NEXP;
        float4 w0 = ld4f(wrow);
        float4 w1 = ld4f(wrow + 4);
        acc[0] = fmaf(xv, w0.x, acc[0]); acc[1] = fmaf(xv, w0.y, acc[1]);
        acc[2] = fmaf(xv, w0.z, acc[2]); acc[3] = fmaf(xv, w0.w, acc[3]);
        acc[4] = fmaf(xv, w1.x, acc[4]); acc[5] = fmaf(xv, w1.y, acc[5]);
        acc[6] = fmaf(xv, w1.z, acc[6]); acc[7] = fmaf(xv, w1.w, acc[7]);
    }
#pragma unroll
    for (int off = 32; off > 0; off >>= 1)
#pragma unroll
        for (int e = 0; e < NEXP; ++e) acc[e] += __shfl_xor(acc[e], off);

    if (lane == 0) {
        float l[NEXP];
#pragma unroll
        for (int e = 0; e < NEXP; ++e) l[e] = acc[e] + br[e];
        int e0 = 0;
#pragma unroll
        for (int e = 1; e < NEXP; ++e) if (l[e] > l[e0]) e0 = e;
        int e1 = (e0 == 0) ? 1 : 0;
#pragma unroll
        for (int e = 0; e < NEXP; ++e) if (e != e0 && l[e] > l[e1]) e1 = e;
        float g0 = 1.0f / (1.0f + expf(l[e1] - l[e0]));
        tok_e[t] = e0 | (e1 << 8);
        tok_g[t] = g0;
    }
}

// ---------------- ballot-aggregated histogram (<=8 atomics per wave) ---------
__global__ __launch_bounds__(256) void hist_kernel(const int* __restrict__ tok_e,
                                                   int* __restrict__ cnt) {
    int t = blockIdx.x * 256 + threadIdx.x;        // grid sized exactly NTOK
    int lane = threadIdx.x & 63;
    int pk = tok_e[t];
    int e0 = pk & 0xff, e1 = (pk >> 8) & 0xff;
#pragma unroll
    for (int e = 0; e < NEXP; ++e) {
        unsigned long long m0 = __ballot(e0 == e);
        unsigned long long m1 = __ballot(e1 == e);
        int c = __popcll(m0) + __popcll(m1);
        if (lane == 0 && c) atomicAdd(&cnt[e], c);
    }
}

// ---------------- 8-entry prefix scan ----------------------------------------
__global__ void scan_kernel(const int* __restrict__ cnt, int* __restrict__ offs,
                            int* __restrict__ cnt2) {
    if (threadIdx.x == 0) {
        int s = 0;
#pragma unroll
        for (int e = 0; e < NEXP; ++e) { offs[e] = s; s += cnt[e]; }
        offs[NEXP] = s;
    }
    if (threadIdx.x < NEXP) cnt2[threadIdx.x] = 0;
}

// ---------------- ballot-ranked list build (1 atomic/wave/expert) ------------
__global__ __launch_bounds__(256) void build_lists(
    const int* __restrict__ tok_e, const float* __restrict__ tok_g,
    const int* __restrict__ offs, int* __restrict__ cnt2,
    int* __restrict__ tok_list, float* __restrict__ gate_list)
{
    int t = blockIdx.x * 256 + threadIdx.x;        // grid sized exactly NTOK
    int lane = threadIdx.x & 63;
    unsigned long long lt = (lane == 63) ? 0x7fffffffffffffffull
                                         : (((unsigned long long)1 << lane) - 1);
    int pk = tok_e[t];
    float g0 = tok_g[t];
    int e0 = pk & 0xff, e1 = (pk >> 8) & 0xff;
    int pos0 = 0, pos1 = 0;
#pragma unroll
    for (int e = 0; e < NEXP; ++e) {
        unsigned long long m0 = __ballot(e0 == e);
        unsigned long long m1 = __ballot(e1 == e);
        int c = __popcll(m0) + __popcll(m1);
        int base = 0;
        if (lane == 0 && c) base = atomicAdd(&cnt2[e], c);
        base = __shfl(base, 0);
        if (e0 == e) pos0 = offs[e] + base + __popcll(m0 & lt);
        if (e1 == e) pos1 = offs[e] + base + __popcll(m0) + __popcll(m1 & lt);
    }
    tok_list[pos0] = t; gate_list[pos0] = g0;
    tok_list[pos1] = t; gate_list[pos1] = 1.0f - g0;
}

// ---------------- MFMA GEMM, 3-stage pipelined, LDS dbuf ---------------------
// 128x128 tile, BK=32, 256 thr = 4 waves (2x2), wave = 4x4 frags 16x16x32 bf16.
// LDS rows padded to 40 shorts (80B = 20-bank stride): frag reads hit each of
// the 32 banks exactly 8x per wave (5r mod 8 is a permutation) -> conflict-free.
// Pipeline: iter t: write LDS[(t+1)&1] (regs from t-1) -> issue loads(t+2)
// -> ds_read+MFMA tile t -> ONE barrier.
template <int K, int N, bool GATHER, bool EPI2, typename AT>
__global__ __launch_bounds__(256) void moe_gemm_mfma(
    const AT* __restrict__ Abase,
    const float* __restrict__ Wall,
    const float* __restrict__ biasall,
    const int* __restrict__ offs,
    const int* __restrict__ tok_list,
    const float* __restrict__ gate_list,
    void* __restrict__ outp)
{
    const int e = blockIdx.z;
    const int rbase = offs[e];
    const int rows = offs[e + 1] - rbase;
    const int rt = blockIdx.y * 128;
    if (rt >= rows) return;
    const int ct = blockIdx.x * 128;
    const float* __restrict__ W = Wall + (size_t)e * K * N;

    __shared__ __align__(16) unsigned short As[2][128][40];
    __shared__ __align__(16) unsigned short Bs[2][128][40];

    const int tid = threadIdx.x;
    const int lane = tid & 63;
    const int wv = tid >> 6;
    const int wr = wv >> 1, wc = wv & 1;

    const int srow = tid >> 1;          // 0..127
    const int skh = tid & 1;            // k-half
    int ar = rt + srow; if (ar > rows - 1) ar = rows - 1;
    const AT* __restrict__ aptr;
    if (GATHER) aptr = Abase + (size_t)tok_list[rbase + ar] * K + skh * 16;
    else        aptr = Abase + (size_t)(rbase + ar) * K + skh * 16;
    const float* __restrict__ bptr = W + (size_t)skh * 16 * N + ct + srow;

    const int fr = lane & 15;
    const int fs = lane >> 4;

    f32x4 acc[4][4];
    const f32x4 vz = {0.f, 0.f, 0.f, 0.f};
#pragma unroll
    for (int m = 0; m < 4; ++m)
#pragma unroll
        for (int n = 0; n < 4; ++n) acc[m][n] = vz;

    // payload registers (live across one iteration)
    float pa[16];       // f32 A path
    uint4 pau0, pau1;   // bf16 A path
    float pb[16];

    auto issue = [&](int t) {
        if constexpr (sizeof(AT) == 4) {
            const float* ap = (const float*)aptr + t * 32;
            float4 a0 = ld4f(ap), a1 = ld4f(ap + 4), a2 = ld4f(ap + 8), a3 = ld4f(ap + 12);
            pa[0] = a0.x; pa[1] = a0.y; pa[2] = a0.z; pa[3] = a0.w;
            pa[4] = a1.x; pa[5] = a1.y; pa[6] = a1.z; pa[7] = a1.w;
            pa[8] = a2.x; pa[9] = a2.y; pa[10] = a2.z; pa[11] = a2.w;
            pa[12] = a3.x; pa[13] = a3.y; pa[14] = a3.z; pa[15] = a3.w;
        } else {
            const AT* ap = aptr + t * 32;
            pau0 = *reinterpret_cast<const uint4*>(ap);
            pau1 = *reinterpret_cast<const uint4*>(ap + 8);
        }
        const float* bp = bptr + (size_t)t * 32 * N;
#pragma unroll
        for (int j = 0; j < 16; ++j) pb[j] = bp[(size_t)j * N];
    };

    auto writeLDS = [&](int buf) {
        uint4 wa0, wa1;
        if constexpr (sizeof(AT) == 4) {
            wa0 = make_uint4(pk2(pa[0], pa[1]), pk2(pa[2], pa[3]),
                             pk2(pa[4], pa[5]), pk2(pa[6], pa[7]));
            wa1 = make_uint4(pk2(pa[8], pa[9]), pk2(pa[10], pa[11]),
                             pk2(pa[12], pa[13]), pk2(pa[14], pa[15]));
        } else { wa0 = pau0; wa1 = pau1; }
        uint4 wb0 = make_uint4(pk2(pb[0], pb[1]), pk2(pb[2], pb[3]),
                               pk2(pb[4], pb[5]), pk2(pb[6], pb[7]));
        uint4 wb1 = make_uint4(pk2(pb[8], pb[9]), pk2(pb[10], pb[11]),
                               pk2(pb[12], pb[13]), pk2(pb[14], pb[15]));
        *reinterpret_cast<uint4*>(&As[buf][srow][skh * 16 + 0]) = wa0;
        *reinterpret_cast<uint4*>(&As[buf][srow][skh * 16 + 8]) = wa1;
        *reinterpret_cast<uint4*>(&Bs[buf][srow][skh * 16 + 0]) = wb0;
        *reinterpret_cast<uint4*>(&Bs[buf][srow][skh * 16 + 8]) = wb1;
    };

    constexpr int NT = K / 32;

    // prologue
    issue(0);
    writeLDS(0);
    issue(1);                    // NT >= 2 always here
    __syncthreads();

    for (int t = 0; t < NT; ++t) {
        const int cur = t & 1;
        if (t + 1 < NT) {
            writeLDS(cur ^ 1);               // tile t+1 (loaded at t-1/prologue)
            if (t + 2 < NT) issue(t + 2);    // in flight across MFMA below
        }
        bf16x8 af[4], bfr[4];
#pragma unroll
        for (int m = 0; m < 4; ++m)
            af[m] = *reinterpret_cast<const bf16x8*>(&As[cur][wr * 64 + m * 16 + fr][fs * 8]);
#pragma unroll
        for (int n = 0; n < 4; ++n)
            bfr[n] = *reinterpret_cast<const bf16x8*>(&Bs[cur][wc * 64 + n * 16 + fr][fs * 8]);
#pragma unroll
        for (int m = 0; m < 4; ++m)
#pragma unroll
            for (int n = 0; n < 4; ++n)
                acc[m][n] = __builtin_amdgcn_mfma_f32_16x16x32_bf16(af[m], bfr[n], acc[m][n], 0, 0, 0);
        __syncthreads();
    }

    // ---- epilogue: C/D map col=lane&15, row=(lane>>4)*4+j (m89 verified) ----
    float bv[4];
#pragma unroll
    for (int n = 0; n < 4; ++n)
        bv[n] = biasall[(size_t)e * N + ct + wc * 64 + n * 16 + fr];

    if constexpr (!EPI2) {
        __hip_bfloat16* h = (__hip_bfloat16*)outp;
#pragma unroll
        for (int m = 0; m < 4; ++m)
#pragma unroll
            for (int j = 0; j < 4; ++j) {
                int rl = rt + wr * 64 + m * 16 + fs * 4 + j;
                if (rl >= rows) continue;
                size_t ro = (size_t)(rbase + rl) * N + ct + wc * 64 + fr;
#pragma unroll
                for (int n = 0; n < 4; ++n) {
                    float v = acc[m][n][j] + bv[n];
                    h[ro + n * 16] = __float2bfloat16(fmaxf(v, 0.f));
                }
            }
    } else {
        float* out = (float*)outp;
#pragma unroll
        for (int m = 0; m < 4; ++m)
#pragma unroll
            for (int j = 0; j < 4; ++j) {
                int rl = rt + wr * 64 + m * 16 + fs * 4 + j;
                if (rl >= rows) continue;
                int rr = rbase + rl;
                int tok = tok_list[rr];
                float g = gate_list[rr];
                size_t o = (size_t)tok * N + ct + wc * 64 + fr;
#pragma unroll
                for (int n = 0; n < 4; ++n)
                    atomicAdd(&out[o + n * 16], g * (acc[m][n][j] + bv[n]));
            }
    }
}

// ---------------- host launcher ----------------------------------------------
extern "C" void kernel_launch(void* const* d_in, const int* in_sizes, int n_in,
                              void* d_out, int out_size, void* d_ws, size_t ws_size,
                              hipStream_t stream)
{
    const float* x  = (const float*)d_in[0];
    const float* Wr = (const float*)d_in[1];
    const float* br = (const float*)d_in[2];
    const float* W1 = (const float*)d_in[3];
    const float* b1 = (const float*)d_in[4];
    const float* W2 = (const float*)d_in[5];
    const float* b2 = (const float*)d_in[6];
    float* out = (float*)d_out;

    char* ws = (char*)d_ws;
    int*   cnt       = (int*)ws;                 // 8 (hist) + 8 (cnt2) zeroed in zero_kernel
    int*   cnt2      = cnt + 8;
    int*   offs      = cnt + 16;                 // 9
    int*   tok_e     = (int*)(ws + 128);                         // NTOK
    float* tok_g     = (float*)(ws + 128 + (size_t)NTOK * 4);    // NTOK
    int*   tok_list  = (int*)(ws + 128 + (size_t)NTOK * 8);      // 2*NTOK
    float* gate_list = (float*)(ws + 128 + (size_t)NTOK * 8 + (size_t)2 * NTOK * 4);
    size_t hoff = ((size_t)128 + (size_t)NTOK * 8 + (size_t)2 * NTOK * 8 + 255) & ~(size_t)255;
    __hip_bfloat16* h = (__hip_bfloat16*)(ws + hoff);   // [2*NTOK][H2] bf16, ~67 MB

    zero_kernel<<<2048, 256, 0, stream>>>((float4*)out, (long)NTOK * HIDDEN / 4, cnt);
    router_kernel<<<NTOK, 64, 0, stream>>>(x, Wr, br, tok_e, tok_g);
    hist_kernel<<<NTOK / 256, 256, 0, stream>>>(tok_e, cnt);
    scan_kernel<<<1, 64, 0, stream>>>(cnt, offs, cnt2);
    build_lists<<<NTOK / 256, 256, 0, stream>>>(tok_e, tok_g, offs, cnt2,
                                                tok_list, gate_list);

    dim3 g1(H2 / 128, NTOK / 128, NEXP);
    dim3 g2(HIDDEN / 128, NTOK / 128, NEXP);
    moe_gemm_mfma<HIDDEN, H2, true,  false, float>
        <<<g1, 256, 0, stream>>>(x, W1, b1, offs, tok_list, gate_list, (void*)h);
    moe_gemm_mfma<H2, HIDDEN, false, true, __hip_bfloat16>
        <<<g2, 256, 0, stream>>>(h, W2, b2, offs, tok_list, gate_list, (void*)out);
}

// Round 7
// 661.017 us; speedup vs baseline: 3.3320x; 1.0326x over previous
//
#include <hip/hip_runtime.h>
#include <hip/hip_bf16.h>
#include <cstddef>
#include <cstdint>

#define HIDDEN 1024
#define H2     2048
#define NEXP   8
#define NTOK   8192

typedef __attribute__((ext_vector_type(8))) short bf16x8;
typedef __attribute__((ext_vector_type(4))) float f32x4;

// ---------------- helpers ----------------------------------------------------
__device__ __forceinline__ float4 ld4f(const float* p) {
    return *reinterpret_cast<const float4*>(p);
}
__device__ __forceinline__ unsigned short f2bf(float f) {
    __hip_bfloat16 b = __float2bfloat16(f);
    unsigned short u; __builtin_memcpy(&u, &b, 2); return u;
}
__device__ __forceinline__ unsigned pk2(float a, float b) {
    return (unsigned)f2bf(a) | ((unsigned)f2bf(b) << 16);
}

// ---------------- zero output + counters -------------------------------------
__global__ void zero_kernel(float4* __restrict__ out4, long n4, int* __restrict__ cnt) {
    long i = (long)blockIdx.x * blockDim.x + threadIdx.x;
    long stride = (long)gridDim.x * blockDim.x;
    float4 z; z.x = z.y = z.z = z.w = 0.f;
    for (; i < n4; i += stride) out4[i] = z;
    if (blockIdx.x == 0 && threadIdx.x < 2 * NEXP) cnt[threadIdx.x] = 0;
}

// ---------------- router: 1 wave per token (no atomics) ----------------------
__global__ __launch_bounds__(64) void router_kernel(
    const float* __restrict__ x, const float* __restrict__ Wr,
    const float* __restrict__ br,
    int* __restrict__ tok_e, float* __restrict__ tok_g)
{
    const int t = blockIdx.x;
    const int lane = threadIdx.x;
    const float* __restrict__ xr = x + (size_t)t * HIDDEN;
    float acc[NEXP];
#pragma unroll
    for (int e = 0; e < NEXP; ++e) acc[e] = 0.f;
#pragma unroll
    for (int i = 0; i < HIDDEN / 64; ++i) {
        int d = i * 64 + lane;
        float xv = xr[d];
        const float* wrow = Wr + (size_t)d * NEXP;
        float4 w0 = ld4f(wrow);
        float4 w1 = ld4f(wrow + 4);
        acc[0] = fmaf(xv, w0.x, acc[0]); acc[1] = fmaf(xv, w0.y, acc[1]);
        acc[2] = fmaf(xv, w0.z, acc[2]); acc[3] = fmaf(xv, w0.w, acc[3]);
        acc[4] = fmaf(xv, w1.x, acc[4]); acc[5] = fmaf(xv, w1.y, acc[5]);
        acc[6] = fmaf(xv, w1.z, acc[6]); acc[7] = fmaf(xv, w1.w, acc[7]);
    }
#pragma unroll
    for (int off = 32; off > 0; off >>= 1)
#pragma unroll
        for (int e = 0; e < NEXP; ++e) acc[e] += __shfl_xor(acc[e], off);

    if (lane == 0) {
        float l[NEXP];
#pragma unroll
        for (int e = 0; e < NEXP; ++e) l[e] = acc[e] + br[e];
        int e0 = 0;
#pragma unroll
        for (int e = 1; e < NEXP; ++e) if (l[e] > l[e0]) e0 = e;
        int e1 = (e0 == 0) ? 1 : 0;
#pragma unroll
        for (int e = 0; e < NEXP; ++e) if (e != e0 && l[e] > l[e1]) e1 = e;
        float g0 = 1.0f / (1.0f + expf(l[e1] - l[e0]));
        tok_e[t] = e0 | (e1 << 8);
        tok_g[t] = g0;
    }
}

// ---------------- ballot-aggregated histogram (<=8 atomics per wave) ---------
__global__ __launch_bounds__(256) void hist_kernel(const int* __restrict__ tok_e,
                                                   int* __restrict__ cnt) {
    int t = blockIdx.x * 256 + threadIdx.x;
    int lane = threadIdx.x & 63;
    int pk = tok_e[t];
    int e0 = pk & 0xff, e1 = (pk >> 8) & 0xff;
#pragma unroll
    for (int e = 0; e < NEXP; ++e) {
        unsigned long long m0 = __ballot(e0 == e);
        unsigned long long m1 = __ballot(e1 == e);
        int c = __popcll(m0) + __popcll(m1);
        if (lane == 0 && c) atomicAdd(&cnt[e], c);
    }
}

// ---------------- 8-entry prefix scan ----------------------------------------
__global__ void scan_kernel(const int* __restrict__ cnt, int* __restrict__ offs,
                            int* __restrict__ cnt2) {
    if (threadIdx.x == 0) {
        int s = 0;
#pragma unroll
        for (int e = 0; e < NEXP; ++e) { offs[e] = s; s += cnt[e]; }
        offs[NEXP] = s;
    }
    if (threadIdx.x < NEXP) cnt2[threadIdx.x] = 0;
}

// ---------------- ballot-ranked list build (1 atomic/wave/expert) ------------
__global__ __launch_bounds__(256) void build_lists(
    const int* __restrict__ tok_e, const float* __restrict__ tok_g,
    const int* __restrict__ offs, int* __restrict__ cnt2,
    int* __restrict__ tok_list, float* __restrict__ gate_list)
{
    int t = blockIdx.x * 256 + threadIdx.x;
    int lane = threadIdx.x & 63;
    unsigned long long lt = (lane == 63) ? 0x7fffffffffffffffull
                                         : (((unsigned long long)1 << lane) - 1);
    int pk = tok_e[t];
    float g0 = tok_g[t];
    int e0 = pk & 0xff, e1 = (pk >> 8) & 0xff;
    int pos0 = 0, pos1 = 0;
#pragma unroll
    for (int e = 0; e < NEXP; ++e) {
        unsigned long long m0 = __ballot(e0 == e);
        unsigned long long m1 = __ballot(e1 == e);
        int c = __popcll(m0) + __popcll(m1);
        int base = 0;
        if (lane == 0 && c) base = atomicAdd(&cnt2[e], c);
        base = __shfl(base, 0);
        if (e0 == e) pos0 = offs[e] + base + __popcll(m0 & lt);
        if (e1 == e) pos1 = offs[e] + base + __popcll(m0) + __popcll(m1 & lt);
    }
    tok_list[pos0] = t; gate_list[pos0] = g0;
    tok_list[pos1] = t; gate_list[pos1] = 1.0f - g0;
}

// ---------------- MFMA GEMM: 256x256 tile, 8 waves, 3-stage pipeline ---------
// BK=32; 512 thr = 8 waves (2 row x 4 col), wave tile 128x64 = 8x4 frags of
// 16x16x32 bf16 -> 32 MFMA/iter/wave (2x R6's MFMA:staging ratio).
// LDS rows padded to 40 shorts (80B = 20-bank stride, conflict-free reads).
// KS-way split-K (EPI2 only): blockIdx.z = e + 8*kz; bias added by kz==0.
template <int K, int N, int KS, bool GATHER, bool EPI2, typename AT>
__global__ __launch_bounds__(512, 2) void moe_gemm_mfma(
    const AT* __restrict__ Abase,
    const float* __restrict__ Wall,
    const float* __restrict__ biasall,
    const int* __restrict__ offs,
    const int* __restrict__ tok_list,
    const float* __restrict__ gate_list,
    void* __restrict__ outp)
{
    const int e = blockIdx.z & 7;
    const int kz = blockIdx.z >> 3;
    constexpr int KSEG = K / KS;
    const int kbase = kz * KSEG;
    const int rbase = offs[e];
    const int rows = offs[e + 1] - rbase;
    const int rt = blockIdx.y * 256;
    if (rt >= rows) return;
    const int ct = blockIdx.x * 256;
    const float* __restrict__ W = Wall + (size_t)e * K * N;

    __shared__ __align__(16) unsigned short As[2][256][40];
    __shared__ __align__(16) unsigned short Bs[2][256][40];

    const int tid = threadIdx.x;
    const int lane = tid & 63;
    const int wv = tid >> 6;            // 0..7
    const int wr = wv >> 2, wc = wv & 3;

    const int srow = tid >> 1;          // 0..255
    const int skh = tid & 1;            // k-half (16 each)
    int ar = rt + srow; if (ar > rows - 1) ar = rows - 1;
    const AT* __restrict__ aptr;
    if (GATHER) aptr = Abase + (size_t)tok_list[rbase + ar] * K + kbase + skh * 16;
    else        aptr = Abase + (size_t)(rbase + ar) * K + kbase + skh * 16;
    const float* __restrict__ bptr = W + (size_t)(kbase + skh * 16) * N + ct + srow;

    const int fr = lane & 15;
    const int fs = lane >> 4;

    f32x4 acc[8][4];
    const f32x4 vz = {0.f, 0.f, 0.f, 0.f};
#pragma unroll
    for (int m = 0; m < 8; ++m)
#pragma unroll
        for (int n = 0; n < 4; ++n) acc[m][n] = vz;

    float pa[16];       // f32 A path
    uint4 pau0, pau1;   // bf16 A path
    float pb[16];

    auto issue = [&](int t) {
        if constexpr (sizeof(AT) == 4) {
            const float* ap = (const float*)aptr + t * 32;
            float4 a0 = ld4f(ap), a1 = ld4f(ap + 4), a2 = ld4f(ap + 8), a3 = ld4f(ap + 12);
            pa[0] = a0.x; pa[1] = a0.y; pa[2] = a0.z; pa[3] = a0.w;
            pa[4] = a1.x; pa[5] = a1.y; pa[6] = a1.z; pa[7] = a1.w;
            pa[8] = a2.x; pa[9] = a2.y; pa[10] = a2.z; pa[11] = a2.w;
            pa[12] = a3.x; pa[13] = a3.y; pa[14] = a3.z; pa[15] = a3.w;
        } else {
            const AT* ap = aptr + t * 32;
            pau0 = *reinterpret_cast<const uint4*>(ap);
            pau1 = *reinterpret_cast<const uint4*>(ap + 8);
        }
        const float* bp = bptr + (size_t)t * 32 * N;
#pragma unroll
        for (int j = 0; j < 16; ++j) pb[j] = bp[(size_t)j * N];
    };

    auto writeLDS = [&](int buf) {
        uint4 wa0, wa1;
        if constexpr (sizeof(AT) == 4) {
            wa0 = make_uint4(pk2(pa[0], pa[1]), pk2(pa[2], pa[3]),
                             pk2(pa[4], pa[5]), pk2(pa[6], pa[7]));
            wa1 = make_uint4(pk2(pa[8], pa[9]), pk2(pa[10], pa[11]),
                             pk2(pa[12], pa[13]), pk2(pa[14], pa[15]));
        } else { wa0 = pau0; wa1 = pau1; }
        uint4 wb0 = make_uint4(pk2(pb[0], pb[1]), pk2(pb[2], pb[3]),
                               pk2(pb[4], pb[5]), pk2(pb[6], pb[7]));
        uint4 wb1 = make_uint4(pk2(pb[8], pb[9]), pk2(pb[10], pb[11]),
                               pk2(pb[12], pb[13]), pk2(pb[14], pb[15]));
        *reinterpret_cast<uint4*>(&As[buf][srow][skh * 16 + 0]) = wa0;
        *reinterpret_cast<uint4*>(&As[buf][srow][skh * 16 + 8]) = wa1;
        *reinterpret_cast<uint4*>(&Bs[buf][srow][skh * 16 + 0]) = wb0;
        *reinterpret_cast<uint4*>(&Bs[buf][srow][skh * 16 + 8]) = wb1;
    };

    constexpr int NT = KSEG / 32;

    issue(0);
    writeLDS(0);
    issue(1);
    __syncthreads();

    for (int t = 0; t < NT; ++t) {
        const int cur = t & 1;
        if (t + 1 < NT) {
            writeLDS(cur ^ 1);
            if (t + 2 < NT) issue(t + 2);
        }
        bf16x8 af[8], bfr[4];
#pragma unroll
        for (int m = 0; m < 8; ++m)
            af[m] = *reinterpret_cast<const bf16x8*>(&As[cur][wr * 128 + m * 16 + fr][fs * 8]);
#pragma unroll
        for (int n = 0; n < 4; ++n)
            bfr[n] = *reinterpret_cast<const bf16x8*>(&Bs[cur][wc * 64 + n * 16 + fr][fs * 8]);
#pragma unroll
        for (int m = 0; m < 8; ++m)
#pragma unroll
            for (int n = 0; n < 4; ++n)
                acc[m][n] = __builtin_amdgcn_mfma_f32_16x16x32_bf16(af[m], bfr[n], acc[m][n], 0, 0, 0);
        __syncthreads();
    }

    // ---- epilogue: C/D map col=lane&15, row=(lane>>4)*4+j (m89 verified) ----
    float bv[4];
#pragma unroll
    for (int n = 0; n < 4; ++n)
        bv[n] = (EPI2 && kz != 0) ? 0.f
              : biasall[(size_t)e * N + ct + wc * 64 + n * 16 + fr];

    if constexpr (!EPI2) {
        __hip_bfloat16* h = (__hip_bfloat16*)outp;
#pragma unroll
        for (int m = 0; m < 8; ++m)
#pragma unroll
            for (int j = 0; j < 4; ++j) {
                int rl = rt + wr * 128 + m * 16 + fs * 4 + j;
                if (rl >= rows) continue;
                size_t ro = (size_t)(rbase + rl) * N + ct + wc * 64 + fr;
#pragma unroll
                for (int n = 0; n < 4; ++n) {
                    float v = acc[m][n][j] + bv[n];
                    h[ro + n * 16] = __float2bfloat16(fmaxf(v, 0.f));
                }
            }
    } else {
        float* out = (float*)outp;
#pragma unroll
        for (int m = 0; m < 8; ++m)
#pragma unroll
            for (int j = 0; j < 4; ++j) {
                int rl = rt + wr * 128 + m * 16 + fs * 4 + j;
                if (rl >= rows) continue;
                int rr = rbase + rl;
                int tok = tok_list[rr];
                float g = gate_list[rr];
                size_t o = (size_t)tok * N + ct + wc * 64 + fr;
#pragma unroll
                for (int n = 0; n < 4; ++n)
                    atomicAdd(&out[o + n * 16], g * (acc[m][n][j] + bv[n]));
            }
    }
}

// ---------------- host launcher ----------------------------------------------
extern "C" void kernel_launch(void* const* d_in, const int* in_sizes, int n_in,
                              void* d_out, int out_size, void* d_ws, size_t ws_size,
                              hipStream_t stream)
{
    const float* x  = (const float*)d_in[0];
    const float* Wr = (const float*)d_in[1];
    const float* br = (const float*)d_in[2];
    const float* W1 = (const float*)d_in[3];
    const float* b1 = (const float*)d_in[4];
    const float* W2 = (const float*)d_in[5];
    const float* b2 = (const float*)d_in[6];
    float* out = (float*)d_out;

    char* ws = (char*)d_ws;
    int*   cnt       = (int*)ws;
    int*   cnt2      = cnt + 8;
    int*   offs      = cnt + 16;
    int*   tok_e     = (int*)(ws + 128);
    float* tok_g     = (float*)(ws + 128 + (size_t)NTOK * 4);
    int*   tok_list  = (int*)(ws + 128 + (size_t)NTOK * 8);
    float* gate_list = (float*)(ws + 128 + (size_t)NTOK * 8 + (size_t)2 * NTOK * 4);
    size_t hoff = ((size_t)128 + (size_t)NTOK * 8 + (size_t)2 * NTOK * 8 + 255) & ~(size_t)255;
    __hip_bfloat16* h = (__hip_bfloat16*)(ws + hoff);   // [2*NTOK][H2] bf16, ~67 MB

    zero_kernel<<<2048, 256, 0, stream>>>((float4*)out, (long)NTOK * HIDDEN / 4, cnt);
    router_kernel<<<NTOK, 64, 0, stream>>>(x, Wr, br, tok_e, tok_g);
    hist_kernel<<<NTOK / 256, 256, 0, stream>>>(tok_e, cnt);
    scan_kernel<<<1, 64, 0, stream>>>(cnt, offs, cnt2);
    build_lists<<<NTOK / 256, 256, 0, stream>>>(tok_e, tok_g, offs, cnt2,
                                                tok_list, gate_list);

    // gemm1: 256x256 tiles, no split-K (relu epilogue). 8x64x8 grid.
    dim3 g1(H2 / 256, (2 * NTOK) / 256, NEXP);
    // gemm2: 256x256 tiles, split-K=2 (atomic epilogue). 4x64x16 grid.
    dim3 g2(HIDDEN / 256, (2 * NTOK) / 256, NEXP * 2);
    moe_gemm_mfma<HIDDEN, H2, 1, true,  false, float>
        <<<g1, 512, 0, stream>>>(x, W1, b1, offs, tok_list, gate_list, (void*)h);
    moe_gemm_mfma<H2, HIDDEN, 2, false, true, __hip_bfloat16>
        <<<g2, 512, 0, stream>>>(h, W2, b2, offs, tok_list, gate_list, (void*)out);
}